// Round 1
// baseline (2430.021 us; speedup 1.0000x reference)
//
#include <hip/hip_runtime.h>

#define T_TOK 8192   // B*S tokens
#define DIM   768
#define NCB   8192   // codebook entries
#define KSEL  8
#define BT    64     // tokens per workgroup
#define BN    128    // codes per tile
#define BD    32     // d-chunk staged in LDS
#define NQ    (BD/4) // 8 k-quads per chunk
#define DSTR  140    // dist row stride in floats (16B-aligned, 2-way banks)
#define BUFQ  1536   // float4 per staging buffer: xs 512 + cs 1024

typedef float v2f __attribute__((ext_vector_type(2)));

// 16B global->LDS DMA. Dest is wave-uniform base + lane*16 (HW rule); all
// per-lane scatter/swizzle lives in the GLOBAL source address.
__device__ __forceinline__ void gload16(const float* g, float4* l) {
  __builtin_amdgcn_global_load_lds(
      (const __attribute__((address_space(1))) void*)g,
      (__attribute__((address_space(3))) void*)l, 16, 0, 0);
}

// ---------------------------------------------------------------------------
// Kernel A: ||row||^2 — bit-exact modern-numpy pairwise_sum (npyv/AVX-512
// W=16) over t[k]=fl32(v*v). [frozen: R5 green — do not change rounding]
// ---------------------------------------------------------------------------
__global__ __launch_bounds__(256) void sq_pairwise_kernel(
    const float* __restrict__ cb, const float* __restrict__ x,
    float* __restrict__ c2out, float* __restrict__ x2out)
{
  #pragma clang fp contract(off)
  __shared__ float part[32][8];
  const int tid = threadIdx.x;
  const int row = blockIdx.x * 32 + (tid >> 3);       // 0..16383
  const int b   = tid & 7;                            // 96-block index
  const float* src = (row < NCB) ? (cb + (size_t)row * DIM)
                                 : (x + (size_t)(row - NCB) * DIM);
  const float* a = src + 96 * b;

  float s[16];
  #pragma unroll
  for (int l = 0; l < 16; ++l) {
    float v, t;
    v = a[l];       t = v * v; float r0 = t;
    v = a[64 + l];  t = v * v; r0 = r0 + t;
    v = a[80 + l];  t = v * v; r0 = r0 + t;
    v = a[16 + l];  t = v * v; float r1 = t;
    v = a[32 + l];  t = v * v; float r2 = t;
    v = a[48 + l];  t = v * v; float r3 = t;
    s[l] = (r0 + r1) + (r2 + r3);
  }
  float t1[8], t2[4];
  #pragma unroll
  for (int i = 0; i < 8; ++i) t1[i] = s[i] + s[i + 8];
  #pragma unroll
  for (int j = 0; j < 4; ++j) t2[j] = t1[j] + t1[j + 4];
  part[tid >> 3][b] = (t2[0] + t2[2]) + (t2[1] + t2[3]);
  __syncthreads();

  if (b == 0) {
    const float* p = part[tid >> 3];
    float res = ((p[0] + p[1]) + (p[2] + p[3])) + ((p[4] + p[5]) + (p[6] + p[7]));
    if (row < NCB) c2out[row] = res;
    else           x2out[row - NCB] = res;
  }
}

// ---------------------------------------------------------------------------
// Kernel B: split-K distance + per-split exact top-8.
// Frozen arithmetic (R5): unfused SSE1 4-lane comb (lane = k&3, ascending k),
// reduce (l0+l2)+(l1+l3), neg = fl(fl(2*xc-x2)-c2), key = -neg (exact).
// New this round: double-buffered global_load_lds DMA staging (1 barrier per
// d-chunk instead of 2 + a ds_write drain-fill phase). Staging is lane-linear
// in LDS (DMA requirement); the codebook tile is code-major with an XOR
// swizzle on the quad index, slot = c*8 + (q ^ ((c>>3)&7)):
//   - DMA global sources stay 128B-contiguous per 8 lanes (coalesced),
//   - ds_read_b128 per (q,j) hits 8 distinct bank-quads x2 lanes (2-way=free),
//   - read addr = (csb + gx*64 + (q^g7)) with immediate offset j*128.
// x tile keeps [q][t] layout: read addressing identical to previous version.
// Identical float values, identical op order => bit-exact vs R5 kernel.
// ---------------------------------------------------------------------------
__global__ __launch_bounds__(256, 2) void dist_topk_kernel(
    const float* __restrict__ x, const float* __restrict__ cb,
    const float* __restrict__ c2g, const float* __restrict__ x2g,
    float* __restrict__ ws, int ncodes)
{
  #pragma clang fp contract(off)
  __shared__ float4 smem4[2 * BUFQ];             // 49152 B
  float* smem = (float*)smem4;
  // buf b: xs = smem4 + b*BUFQ (512 f4, [q][t]); cs = xs + 512 (1024 f4)
  // dist overlays [BT][DSTR] floats = 2240 f4; merge overlays 1024 f4

  const int tid  = threadIdx.x;
  const int t0   = blockIdx.x * BT;
  const int nbeg = blockIdx.y * ncodes;

  const int gx = tid & 15;        // 8-code group
  const int gy = tid >> 4;        // 4-token group
  const int g7 = gx & 7;

  const int tt = tid >> 2;        // scan: token 0..63
  const int cc = tid & 3;         // scan: lane 0..3

  const int lane = tid & 63;      // DMA stager
  const int wid  = tid >> 6;

  // x staging: slot s = wid*64+lane -> (quad wid, token lane); second call
  // covers quad wid+4. Source row is fixed per thread for the whole kernel.
  const float* xsrcA = x + (size_t)(t0 + lane) * DIM + wid * 4;
  const float* xsrcB = xsrcA + 16;               // quad wid+4

  // cs staging: call m covers slots m*256+wid*64+lane.
  //   c  = s>>3  (code within tile), stored quad qq = (s&7) ^ ((s>>6)&7)
  const int s0_ = 0 * 256 + wid * 64 + lane;
  const int s1_ = 1 * 256 + wid * 64 + lane;
  const int s2_ = 2 * 256 + wid * 64 + lane;
  const int s3_ = 3 * 256 + wid * 64 + lane;
  const int c0_ = s0_ >> 3, q0_ = (s0_ & 7) ^ ((s0_ >> 6) & 7);
  const int c1_ = s1_ >> 3, q1_ = (s1_ & 7) ^ ((s1_ >> 6) & 7);
  const int c2_ = s2_ >> 3, q2_ = (s2_ & 7) ^ ((s2_ >> 6) & 7);
  const int c3_ = s3_ >> 3, q3_ = (s3_ & 7) ^ ((s3_ >> 6) & 7);

  float x2r[4];
  #pragma unroll
  for (int i = 0; i < 4; ++i) x2r[i] = x2g[t0 + gy * 4 + i];

  float bdist[KSEL]; int bid[KSEL];
  #pragma unroll
  for (int i = 0; i < KSEL; ++i) { bdist[i] = __builtin_inff(); bid[i] = 0x7fffffff; }
  float bmax = __builtin_inff(); int bmaxid = 0x7fffffff; int bslot = 0;

  for (int n0 = nbeg; n0 < nbeg + ncodes; n0 += BN) {
    float c2r[8];
    #pragma unroll
    for (int j = 0; j < 8; ++j) c2r[j] = c2g[n0 + gx * 8 + j];

    v2f accL[4][8], accH[4][8];    // SSE lanes (0,1) and (2,3)
    #pragma unroll
    for (int i = 0; i < 4; ++i)
      #pragma unroll
      for (int j = 0; j < 8; ++j) { accL[i][j] = (v2f)0.f; accH[i][j] = (v2f)0.f; }

    // per-tile codebook DMA source rows (XOR-permuted quad per slot)
    const float* csrc0 = cb + (size_t)(n0 + c0_) * DIM + q0_ * 4;
    const float* csrc1 = cb + (size_t)(n0 + c1_) * DIM + q1_ * 4;
    const float* csrc2 = cb + (size_t)(n0 + c2_) * DIM + q2_ * 4;
    const float* csrc3 = cb + (size_t)(n0 + c3_) * DIM + q3_ * 4;

    __syncthreads();               // prev tile's scan reads done (overlay)
    {                              // stage chunk 0 -> buf0
      float4* xsn = smem4;
      float4* csn = smem4 + 512;
      gload16(xsrcA, xsn + wid * 64);
      gload16(xsrcB, xsn + 256 + wid * 64);
      gload16(csrc0, csn + 0   + wid * 64);
      gload16(csrc1, csn + 256 + wid * 64);
      gload16(csrc2, csn + 512 + wid * 64);
      gload16(csrc3, csn + 768 + wid * 64);
    }
    __syncthreads();               // chunk 0 visible (implicit vmcnt(0))

    for (int d0 = 0; d0 < DIM; d0 += BD) {
      const int buf = (d0 >> 5) & 1;
      const float4* xsb = smem4 + buf * BUFQ;
      const float4* csb = xsb + 512;

      const int dn = d0 + BD;
      if (dn < DIM) {              // issue next-chunk DMA into other buffer
        float4* xsn = smem4 + (buf ^ 1) * BUFQ;
        float4* csn = xsn + 512;
        gload16(xsrcA + dn, xsn + wid * 64);
        gload16(xsrcB + dn, xsn + 256 + wid * 64);
        gload16(csrc0 + dn, csn + 0   + wid * 64);
        gload16(csrc1 + dn, csn + 256 + wid * 64);
        gload16(csrc2 + dn, csn + 512 + wid * 64);
        gload16(csrc3 + dn, csn + 768 + wid * 64);
      }

      #pragma unroll
      for (int q = 0; q < NQ; ++q) {
        float4 xa[4];
        #pragma unroll
        for (int i = 0; i < 4; ++i) xa[i] = xsb[q * BT + gy * 4 + i];
        const float4* cq = csb + gx * 64 + (q ^ g7);   // imm-walk over j
        #pragma unroll
        for (int j = 0; j < 8; ++j) {
          const float4 cv = cq[j * 8];
          #pragma unroll
          for (int i = 0; i < 4; ++i) {
            v2f a, b, p;
            a[0] = xa[i].x; a[1] = xa[i].y;
            b[0] = cv.x;    b[1] = cv.y;
            p = a * b;                      // 2 independent fl32 muls
            accL[i][j] = accL[i][j] + p;    // 2 independent fl32 adds
            a[0] = xa[i].z; a[1] = xa[i].w;
            b[0] = cv.z;    b[1] = cv.w;
            p = a * b;
            accH[i][j] = accH[i][j] + p;
          }
        }
      }
      __syncthreads();             // my DMA landed + everyone's reads done
    }

    // ---- dist write (unchanged arithmetic) ----
    #pragma unroll
    for (int i = 0; i < 4; ++i) {
      float v[8];
      #pragma unroll
      for (int j = 0; j < 8; ++j) {
        // einsum reduce (l0+l2)+(l1+l3), then literal numpy combine
        float xc = (accL[i][j][0] + accH[i][j][0]) + (accL[i][j][1] + accH[i][j][1]);
        float s  = 2.0f * xc - x2r[i];
        v[j] = -(s - c2r[j]);
      }
      float4* dp = (float4*)&smem[(gy * 4 + i) * DSTR + gx * 8];
      dp[0] = make_float4(v[0], v[1], v[2], v[3]);
      dp[1] = make_float4(v[4], v[5], v[6], v[7]);
    }
    __syncthreads();

    // per-lane top-8 (ids ascend in scan; strict < = stable lower-id on ties)
    #pragma unroll
    for (int i2 = 0; i2 < BN / 4; ++i2) {
      const float dval = smem[tt * DSTR + cc + 4 * i2];
      const int   id   = n0 + cc + 4 * i2;
      if (dval < bmax) {
        #pragma unroll
        for (int q = 0; q < KSEL; ++q)
          if (q == bslot) { bdist[q] = dval; bid[q] = id; }
        bmax = bdist[0]; bmaxid = bid[0]; bslot = 0;
        #pragma unroll
        for (int q = 1; q < KSEL; ++q)
          if (bdist[q] > bmax || (bdist[q] == bmax && bid[q] > bmaxid)) {
            bmax = bdist[q]; bmaxid = bid[q]; bslot = q;
          }
      }
    }
    // next tile's staging is gated by the tile-top barrier
  }

  // ---- merge 4 lanes x 8 -> this split's top-8 per token; write to ws ----
  __syncthreads();                     // last scan's dist reads done
  float* md = smem;                    // [64][32] floats
  int*   mi = (int*)smem + 2048;       // [64][32] ints
  #pragma unroll
  for (int j = 0; j < KSEL; ++j) {
    md[tt * 32 + cc * KSEL + j] = bdist[j];
    mi[tt * 32 + cc * KSEL + j] = bid[j];
  }
  __syncthreads();
  if (tid < BT) {
    float* mdt = md + tid * 32;
    int*   mit = mi + tid * 32;
    const size_t base = ((size_t)blockIdx.y * T_TOK + (t0 + tid)) * 16;
    for (int r = 0; r < KSEL; ++r) {
      float best = __builtin_inff(); int bestid = 0x7fffffff; int bs = 0;
      for (int s = 0; s < 32; ++s) {
        const float dv = mdt[s]; const int iv = mit[s];
        if (dv < best || (dv == best && iv < bestid)) { best = dv; bestid = iv; bs = s; }
      }
      mdt[bs] = __builtin_inff();
      ws[base + r] = best;
      ((int*)ws)[base + 8 + r] = bestid;
    }
  }
}

// ---------------------------------------------------------------------------
// Kernel C: exact (val,id)-lex merge of nsplit*8 candidates -> final ids,
// fused with the gather-mean of the 8 selected rows.
// ---------------------------------------------------------------------------
__global__ __launch_bounds__(192) void merge_gather_kernel(
    const float* __restrict__ cb, const float* __restrict__ ws,
    float* __restrict__ out, float* __restrict__ out_ids, int nsplit)
{
  __shared__ float mv[64];
  __shared__ int   mid[64];
  __shared__ int   ssel[KSEL];

  const int t   = blockIdx.x;
  const int tid = threadIdx.x;
  const int ncand = nsplit * KSEL;

  if (tid < ncand) {
    const int s = tid >> 3, r = tid & 7;
    const size_t base = ((size_t)s * T_TOK + t) * 16;
    mv[tid]  = ws[base + r];
    mid[tid] = ((const int*)ws)[base + 8 + r];
  }
  __syncthreads();

  if (tid == 0) {
    for (int r = 0; r < KSEL; ++r) {
      float best = __builtin_inff(); int bestid = 0x7fffffff; int bs = 0;
      for (int s = 0; s < ncand; ++s) {
        const float dv = mv[s]; const int iv = mid[s];
        if (dv < best || (dv == best && iv < bestid)) { best = dv; bestid = iv; bs = s; }
      }
      mv[bs] = __builtin_inff();
      ssel[r] = bestid;
      out_ids[(size_t)t * KSEL + r] = (float)bestid;
    }
  }
  __syncthreads();

  float4 s4 = make_float4(0.f, 0.f, 0.f, 0.f);
  #pragma unroll
  for (int r = 0; r < KSEL; ++r) {
    const float4 v = *(const float4*)(cb + (size_t)ssel[r] * DIM + tid * 4);
    s4.x += v.x; s4.y += v.y; s4.z += v.z; s4.w += v.w;
  }
  s4.x *= 0.125f; s4.y *= 0.125f; s4.z *= 0.125f; s4.w *= 0.125f;
  *(float4*)(out + (size_t)t * DIM + tid * 4) = s4;
}

extern "C" void kernel_launch(void* const* d_in, const int* in_sizes, int n_in,
                              void* d_out, int out_size, void* d_ws, size_t ws_size,
                              hipStream_t stream) {
  (void)in_sizes; (void)n_in; (void)out_size;
  const float* x   = (const float*)d_in[0];
  const float* cbk = (const float*)d_in[1];
  float* out     = (float*)d_out;
  float* c2buf   = out;                   // out[0:8192], overwritten later
  float* x2buf   = out + NCB;             // out[8192:16384], overwritten later
  float* out_ids = out + (size_t)T_TOK * DIM;
  float* ws      = (float*)d_ws;

  int nsplit = 1;
  for (int s = 4; s >= 1; s >>= 1) {
    if ((size_t)s * T_TOK * 16 * 4 <= ws_size) { nsplit = s; break; }
  }
  const int ncodes = NCB / nsplit;

  sq_pairwise_kernel<<<(NCB + T_TOK) / 32, 256, 0, stream>>>(cbk, x, c2buf, x2buf);
  dist_topk_kernel<<<dim3(T_TOK / BT, nsplit), 256, 0, stream>>>(
      x, cbk, c2buf, x2buf, ws, ncodes);
  merge_gather_kernel<<<T_TOK, 192, 0, stream>>>(cbk, ws, out, out_ids, nsplit);
}